// Round 12
// baseline (439.140 us; speedup 1.0000x reference)
//
#include <hip/hip_runtime.h>
#include <cstdint>
#include <cstddef>

#define E_ 8
#define D_ 1024
#define F_ 4096
#define T_ 16384
#define C_ 2048   // tokens per expert

typedef __attribute__((ext_vector_type(8))) short short8;
typedef __attribute__((ext_vector_type(4))) float f32x4;

// fp32 -> bf16 round-to-nearest-even
__device__ __forceinline__ unsigned short f2b(float f) {
  union { float f; uint32_t u; } v; v.f = f;
  uint32_t u = v.u;
  return (unsigned short)((u + 0x7FFFu + ((u >> 16) & 1u)) >> 16);
}

// tanh-approx gelu (jax.nn.gelu default approximate=True)
__device__ __forceinline__ float gelu_t(float x) {
  float u = 0.7978845608028654f * (x + 0.044715f * x * x * x);
  float e = __expf(2.0f * u);
  return 0.5f * x * (2.0f - 2.0f / (e + 1.0f));  // 0.5x(1+tanh(u))
}

__device__ __forceinline__ void gload_lds16(const void* g, void* l) {
  __builtin_amdgcn_global_load_lds(
      (__attribute__((address_space(1))) void*)g,
      (__attribute__((address_space(3))) void*)l, 16, 0, 0);
}

#define MEMFENCE() asm volatile("" ::: "memory")
#define BAR() do { MEMFENCE(); __builtin_amdgcn_s_barrier(); MEMFENCE(); } while (0)

// ---------------- pre-pass: fp32 -> bf16 elementwise ----------------
__global__ void cvt_bf16_kernel(const float* __restrict__ in,
                                unsigned short* __restrict__ out, int n) {
  int idx = blockIdx.x * blockDim.x + threadIdx.x;
  int stride = gridDim.x * blockDim.x;
  for (int i = idx * 8; i < n; i += stride * 8) {
    float4 a = *(const float4*)(in + i);
    float4 b = *(const float4*)(in + i + 4);
    union { unsigned short s[8]; int4 v; } r;
    r.s[0] = f2b(a.x); r.s[1] = f2b(a.y); r.s[2] = f2b(a.z); r.s[3] = f2b(a.w);
    r.s[4] = f2b(b.x); r.s[5] = f2b(b.y); r.s[6] = f2b(b.z); r.s[7] = f2b(b.w);
    *(int4*)(out + i) = r.v;
  }
}

// ---------------- pre-pass: per-expert transpose + convert ----------------
// in: [E][R][Cc] fp32  ->  out: [E][Cc][R] bf16
__global__ void transpose_cvt(const float* __restrict__ in,
                              unsigned short* __restrict__ out, int R, int Cc) {
  __shared__ float tile_s[32][33];
  const int e = blockIdx.y;
  const int ctiles = Cc >> 5;
  const int rt = blockIdx.x / ctiles, ct = blockIdx.x % ctiles;
  const int r0 = rt * 32, c0 = ct * 32;
  const float* ine = in + (size_t)e * R * Cc;
  unsigned short* oute = out + (size_t)e * R * Cc;
  const int tx = threadIdx.x & 31, ty = threadIdx.x >> 5;  // ty in 0..7
#pragma unroll
  for (int q = 0; q < 4; ++q)
    tile_s[ty + q * 8][tx] = ine[(size_t)(r0 + ty + q * 8) * Cc + c0 + tx];
  __syncthreads();
#pragma unroll
  for (int q = 0; q < 4; ++q) {
    float v = tile_s[tx][ty + q * 8];
    oute[(size_t)(c0 + ty + q * 8) * R + r0 + tx] = f2b(v);
  }
}

// ==== 256x256 batched bf16 GEMM, BK=32, ring-4, bank-rotated LDS =========
// A: [E][Mt][Kt] bf16 row-major; B: [E][Nt][Kt] bf16 (row = output column).
// 512 thr = 8 waves (2M x 4N); per-wave 128x64 output; acc[8][4].
// LDS ring: 4 buffers x (A[256][32] + B[256][32]) bf16 = 128 KiB.
// LDS layout: 128B line = rows {2j,2j+1} x 4 k-chunks; content id
// (kchunk<<1)|parity stored at pos = id ^ ((line&3)<<1)  ← bank-ROTATED:
// any 8 consecutive lanes of a fragment read hit 8 distinct pos -> 32 banks.
// Staging linear-dest, inverse-permuted global source (rule #21).
// Loop (r7 champion): reads(t); stage(t+3); MFMA-A0; counted vmcnt;
// one barrier; fax(t+1) prefetch; MFMA-A1.  NO in-loop lgkm drain —
// compiler auto-gates each MFMA operand (fine-grained lgkmcnt), so LDS
// service overlaps the MFMA cluster.
template <int Mt, int Nt, int Kt, int EPI>
__global__ __launch_bounds__(512, 2)
void gemmR(const unsigned short* __restrict__ A,
           const unsigned short* __restrict__ B,
           const float* __restrict__ bias, void* __restrict__ Cout) {
  constexpr int NT = Kt / 32;
  constexpr int MB = Mt / 256, NB = Nt / 256;
  static_assert(NT >= 4, "");

  // bijective XCD swizzle (nwg % 8 == 0 for all our grids)
  const int nwg = E_ * MB * NB;
  const int bid = blockIdx.x;
  const int swzb = (bid & 7) * (nwg >> 3) + (bid >> 3);
  const int e = swzb / (MB * NB);
  const int rem = swzb % (MB * NB);
  const int mblk = rem / NB, nblk = rem % NB;

  const unsigned short* Ae = A + ((size_t)e * Mt + mblk * 256) * Kt;
  const unsigned short* Be = B + ((size_t)e * Nt + nblk * 256) * Kt;

  __shared__ unsigned short lds[65536];  // 128 KiB

  const int tid = threadIdx.x;
  const int lane = tid & 63, wave = tid >> 6;
  const int wm = wave >> 2, wn = wave & 3;  // 2 x 4 wave grid
  const int ls = lane >> 4, lr = lane & 15;

  // staging decode: chunk c in [0,1024): line=c>>3, pos=c&7,
  // id = pos ^ ((line&3)<<1); kchunk = id>>1, parity = id&1;
  // row = 2*line + parity; LDS dest linear c*16B.
  auto decode = [](int c, int& row, int& kc) {
    int line = c >> 3, pos = c & 7;
    int id = pos ^ ((line & 3) << 1);
    row = (line << 1) | (id & 1);
    kc = id >> 1;
  };
  const int c0 = tid, c1 = tid + 512;
  int rA0, kA0, rA1, kA1;
  decode(c0, rA0, kA0); decode(c1, rA1, kA1);

  auto stage = [&](int t) {
    unsigned short* sA = lds + (t & 3) * 16384;
    unsigned short* sB = sA + 8192;
    const int k0 = t * 32;
    gload_lds16(Ae + (size_t)rA0 * Kt + k0 + kA0 * 8, sA + c0 * 8);
    gload_lds16(Ae + (size_t)rA1 * Kt + k0 + kA1 * 8, sA + c1 * 8);
    gload_lds16(Be + (size_t)rA0 * Kt + k0 + kA0 * 8, sB + c0 * 8);
    gload_lds16(Be + (size_t)rA1 * Kt + k0 + kA1 * 8, sB + c1 * 8);
  };

  // bias first (oldest vmem; retired by prologue vmcnt)
  const float* be = bias + (size_t)e * Nt + nblk * 256;
  float bv[4];
#pragma unroll
  for (int n = 0; n < 4; ++n) bv[n] = be[wn * 64 + n * 16 + lr];

  // fragment read offset (shorts): row r, k-chunk ls:
  // line = r>>1; pos = ((ls<<1)|(r&1)) ^ ((line&3)<<1); addr = line*64+pos*8
  auto roff = [&](int r) {
    int line = r >> 1;
    int pos = (((ls << 1) | (r & 1)) ^ ((line & 3) << 1)) & 7;
    return line * 64 + pos * 8;
  };
  int offA0[4], offA1[4], offB[4];
#pragma unroll
  for (int m = 0; m < 4; ++m) {
    offA0[m] = roff(wm * 128 + m * 16 + lr);
    offA1[m] = roff(wm * 128 + 64 + m * 16 + lr);
  }
#pragma unroll
  for (int n = 0; n < 4; ++n) offB[n] = roff(wn * 64 + n * 16 + lr);

  f32x4 acc[8][4] = {};

  stage(0); stage(1); stage(2);
  asm volatile("s_waitcnt vmcnt(8)" ::: "memory");  // bias + tile0 landed
  BAR();

  short8 fax[4], fay[4], fb[4];
  {
    const unsigned short* sA = lds;  // buffer 0
#pragma unroll
    for (int m = 0; m < 4; ++m) fax[m] = *(const short8*)(sA + offA0[m]);
  }

  for (int t = 0; t < NT; ++t) {
    const unsigned short* sA = lds + (t & 3) * 16384;
    const unsigned short* sB = sA + 8192;
#pragma unroll
    for (int n = 0; n < 4; ++n) fb[n] = *(const short8*)(sB + offB[n]);
#pragma unroll
    for (int m = 0; m < 4; ++m) fay[m] = *(const short8*)(sA + offA1[m]);
    if (t + 3 < NT) stage(t + 3);

    __builtin_amdgcn_s_setprio(1);
#pragma unroll
    for (int m = 0; m < 4; ++m)
#pragma unroll
      for (int n = 0; n < 4; ++n)
        acc[m][n] =
            __builtin_amdgcn_mfma_f32_16x16x32_bf16(fax[m], fb[n], acc[m][n], 0, 0, 0);
    __builtin_amdgcn_s_setprio(0);

    if (t + 1 < NT) {
      // counted vmem wait: retire tile t+1's staging (oldest in queue)
      if (t + 3 < NT)      asm volatile("s_waitcnt vmcnt(8)" ::: "memory");
      else if (t + 2 < NT) asm volatile("s_waitcnt vmcnt(4)" ::: "memory");
      else                 asm volatile("s_waitcnt vmcnt(0)" ::: "memory");
      BAR();  // rendezvous: tile t+1 readable; ring distance 4 covers WAR
      const unsigned short* sA2 = lds + ((t + 1) & 3) * 16384;
#pragma unroll
      for (int m = 0; m < 4; ++m)
        fax[m] = *(const short8*)(sA2 + offA0[m]);  // ∥ MFMA A1 below
    }

    __builtin_amdgcn_s_setprio(1);
#pragma unroll
    for (int m = 0; m < 4; ++m)
#pragma unroll
      for (int n = 0; n < 4; ++n)
        acc[4 + m][n] =
            __builtin_amdgcn_mfma_f32_16x16x32_bf16(fay[m], fb[n], acc[4 + m][n], 0, 0, 0);
    __builtin_amdgcn_s_setprio(0);
  }

  asm volatile("s_waitcnt vmcnt(0) lgkmcnt(0)" ::: "memory");
  BAR();  // LDS free for epilogue reuse

  if constexpr (EPI == 1) {
    // bounce: lds as [256][256] ushort, 16B-chunk XOR swizzle (ch ^= row&7)
#pragma unroll
    for (int m = 0; m < 8; ++m)
#pragma unroll
      for (int n = 0; n < 4; ++n)
#pragma unroll
        for (int i = 0; i < 4; ++i) {
          int row = wm * 128 + m * 16 + ls * 4 + i;
          int col = wn * 64 + n * 16 + lr;
          lds[row * 256 + (((col >> 3) ^ (row & 7)) << 3) + (col & 7)] =
              f2b(gelu_t(acc[m][n][i] + bv[n]));
        }
    BAR();
    unsigned short* H = (unsigned short*)Cout;
#pragma unroll
    for (int j = 0; j < 16; ++j) {
      int row = j * 16 + wave * 2 + (lane >> 5);
      int chk = lane & 31;
      int sc = chk ^ (row & 7);
      unsigned short* dst =
          H + ((size_t)e * Mt + mblk * 256 + row) * Nt + nblk * 256 + chk * 8;
      *(int4*)dst = *(const int4*)(lds + row * 256 + sc * 8);
    }
  } else {
    float* O = (float*)Cout;
#pragma unroll
    for (int m = 0; m < 8; ++m)
#pragma unroll
      for (int n = 0; n < 4; ++n)
#pragma unroll
        for (int i = 0; i < 4; ++i) {
          int row = wm * 128 + m * 16 + ls * 4 + i;
          int col = wn * 64 + n * 16 + lr;
          O[((size_t)e * Mt + mblk * 256 + row) * Nt + nblk * 256 + col] =
              acc[m][n][i] + bv[n];
        }
  }
}

extern "C" void kernel_launch(void* const* d_in, const int* in_sizes, int n_in,
                              void* d_out, int out_size, void* d_ws, size_t ws_size,
                              hipStream_t stream) {
  const float* x = (const float*)d_in[0];
  const float* w1 = (const float*)d_in[1];
  const float* b1 = (const float*)d_in[2];
  const float* w2 = (const float*)d_in[3];
  const float* b2 = (const float*)d_in[4];
  float* out = (float*)d_out;

  unsigned short* ws = (unsigned short*)d_ws;
  unsigned short* xb = ws;                               // [T][D] bf16
  unsigned short* w1t = xb + (size_t)T_ * D_;            // [E][F][D] bf16
  unsigned short* w2t = w1t + (size_t)E_ * F_ * D_;      // [E][D][F] bf16
  unsigned short* h = w2t + (size_t)E_ * D_ * F_;        // [T][F] bf16

  cvt_bf16_kernel<<<2048, 256, 0, stream>>>(x, xb, T_ * D_);
  transpose_cvt<<<dim3((D_ / 32) * (F_ / 32), E_), 256, 0, stream>>>(w1, w1t, D_, F_);
  transpose_cvt<<<dim3((F_ / 32) * (D_ / 32), E_), 256, 0, stream>>>(w2, w2t, F_, D_);

  gemmR<C_, F_, D_, 1>
      <<<E_ * (C_ / 256) * (F_ / 256), 512, 0, stream>>>(xb, w1t, b1, h);
  gemmR<C_, D_, F_, 2>
      <<<E_ * (C_ / 256) * (D_ / 256), 512, 0, stream>>>(h, w2t, b2, out);
}

// Round 13
// 424.207 us; speedup vs baseline: 1.0352x; 1.0352x over previous
//
#include <hip/hip_runtime.h>
#include <cstdint>
#include <cstddef>

#define E_ 8
#define D_ 1024
#define F_ 4096
#define T_ 16384
#define C_ 2048   // tokens per expert

typedef __attribute__((ext_vector_type(8))) short short8;
typedef __attribute__((ext_vector_type(4))) float f32x4;

// fp32 -> bf16 round-to-nearest-even
__device__ __forceinline__ unsigned short f2b(float f) {
  union { float f; uint32_t u; } v; v.f = f;
  uint32_t u = v.u;
  return (unsigned short)((u + 0x7FFFu + ((u >> 16) & 1u)) >> 16);
}

// tanh-approx gelu (jax.nn.gelu default approximate=True)
__device__ __forceinline__ float gelu_t(float x) {
  float u = 0.7978845608028654f * (x + 0.044715f * x * x * x);
  float e = __expf(2.0f * u);
  return 0.5f * x * (2.0f - 2.0f / (e + 1.0f));  // 0.5x(1+tanh(u))
}

__device__ __forceinline__ void gload_lds16(const void* g, void* l) {
  __builtin_amdgcn_global_load_lds(
      (__attribute__((address_space(1))) void*)g,
      (__attribute__((address_space(3))) void*)l, 16, 0, 0);
}

// ---------------- pre-pass: fp32 -> bf16 elementwise ----------------
__global__ void cvt_bf16_kernel(const float* __restrict__ in,
                                unsigned short* __restrict__ out, int n) {
  int idx = blockIdx.x * blockDim.x + threadIdx.x;
  int stride = gridDim.x * blockDim.x;
  for (int i = idx * 8; i < n; i += stride * 8) {
    float4 a = *(const float4*)(in + i);
    float4 b = *(const float4*)(in + i + 4);
    union { unsigned short s[8]; int4 v; } r;
    r.s[0] = f2b(a.x); r.s[1] = f2b(a.y); r.s[2] = f2b(a.z); r.s[3] = f2b(a.w);
    r.s[4] = f2b(b.x); r.s[5] = f2b(b.y); r.s[6] = f2b(b.z); r.s[7] = f2b(b.w);
    *(int4*)(out + i) = r.v;
  }
}

// ---------------- pre-pass: per-expert transpose + convert ----------------
// in: [E][R][Cc] fp32  ->  out: [E][Cc][R] bf16
__global__ void transpose_cvt(const float* __restrict__ in,
                              unsigned short* __restrict__ out, int R, int Cc) {
  __shared__ float tile_s[32][33];
  const int e = blockIdx.y;
  const int ctiles = Cc >> 5;
  const int rt = blockIdx.x / ctiles, ct = blockIdx.x % ctiles;
  const int r0 = rt * 32, c0 = ct * 32;
  const float* ine = in + (size_t)e * R * Cc;
  unsigned short* oute = out + (size_t)e * R * Cc;
  const int tx = threadIdx.x & 31, ty = threadIdx.x >> 5;  // ty in 0..7
#pragma unroll
  for (int q = 0; q < 4; ++q)
    tile_s[ty + q * 8][tx] = ine[(size_t)(r0 + ty + q * 8) * Cc + c0 + tx];
  __syncthreads();
#pragma unroll
  for (int q = 0; q < 4; ++q) {
    float v = tile_s[tx][ty + q * 8];
    oute[(size_t)(c0 + ty + q * 8) * R + r0 + tx] = f2b(v);
  }
}

// ==== 256x256 bf16 GEMM — 8 thin phases + GRAY-CODE REGISTER REUSE =======
// r8's proven staging/vmcnt skeleton; per-phase ds_reads now 12/4/8/0 via
// quadrant gray-code (0,0)(0,1)(1,1)(1,0): fa reused 2 phases, both fb sets
// kept live across the 4-phase group. P4/P8 are pure-MFMA phases.
// A: [E][Mt][Kt] bf16 row-major; B: [E][Nt][Kt] bf16 (row = output column).
// 512 thr = 8 waves (2Mx4N per 128x128 quadrant; 64x32 per wave per phase).
// K-tile=64; LDS half-tiles [128][64] bf16, slots A0,A1,B0,B1 per parity;
// +16 KiB pad (144 KiB). Per-row 8-chunk XOR swizzle slot^(row&7) (rule #21).
template <int Mt, int Nt, int Kt, int EPI>
__global__ __launch_bounds__(512, 2)
void gemmG(const unsigned short* __restrict__ A,
           const unsigned short* __restrict__ B,
           const float* __restrict__ bias, void* __restrict__ Cout) {
  constexpr int NT = Kt / 64;       // K-tiles
  constexpr int NI = NT / 2;        // iterations
  constexpr int MB = Mt / 256, NB = Nt / 256;
  static_assert(NT >= 4 && (NT % 2) == 0, "");

  // bijective XCD swizzle (nwg % 8 == 0 for all our grids)
  const int nwg = E_ * MB * NB;
  const int bid = blockIdx.x;
  const int swzb = (bid & 7) * (nwg >> 3) + (bid >> 3);
  const int e = swzb / (MB * NB);
  const int rem = swzb % (MB * NB);
  const int mblk = rem / NB, nblk = rem % NB;

  const unsigned short* Ae = A + ((size_t)e * Mt + mblk * 256) * Kt;
  const unsigned short* Be = B + ((size_t)e * Nt + nblk * 256) * Kt;

  __shared__ unsigned short lds[73728];  // 144 KiB (8 half-slots + pad)

  const int tid = threadIdx.x;
  const int lane = tid & 63, wave = tid >> 6;
  const int wm = wave >> 2, wn = wave & 3;  // 2 x 4 within each quadrant
  const int ls = lane >> 4, lr = lane & 15;

  // staging: chunk c in [0,1024) of a half-tile: row=c>>3, slot=c&7,
  // global chunk g = (c&7)^(row&7); LDS dest linear c*16B (both-sides swz).
  const int c0 = tid, c1 = tid + 512;
  const int r0c = c0 >> 3, g0c = (c0 & 7) ^ (r0c & 7);
  const int r1c = c1 >> 3, g1c = (c1 & 7) ^ (r1c & 7);

  auto stA = [&](int rh, int p, int t, bool valid) {
    unsigned short* dst = valid ? (lds + (size_t)(p * 4 + rh) * 8192)
                                : (lds + 65536);
    const int tt = valid ? t : NT - 1;
    const unsigned short* s = Ae + (size_t)rh * 128 * Kt + tt * 64;
    gload_lds16(s + (size_t)r0c * Kt + g0c * 8, dst + c0 * 8);
    gload_lds16(s + (size_t)r1c * Kt + g1c * 8, dst + c1 * 8);
  };
  auto stB = [&](int ch, int p, int t, bool valid) {
    unsigned short* dst = valid ? (lds + (size_t)(p * 4 + 2 + ch) * 8192)
                                : (lds + 65536);
    const int tt = valid ? t : NT - 1;
    const unsigned short* s = Be + (size_t)ch * 128 * Kt + tt * 64;
    gload_lds16(s + (size_t)r0c * Kt + g0c * 8, dst + c0 * 8);
    gload_lds16(s + (size_t)r1c * Kt + g1c * 8, dst + c1 * 8);
  };

  f32x4 acc[2][2][4][2] = {};  // [rh][ch][m][n]

  // bias fragments first (oldest vmem, drained by prologue vmcnt)
  const float* be = bias + (size_t)e * Nt + nblk * 256;
  float bvf[2][2];
#pragma unroll
  for (int ch = 0; ch < 2; ++ch)
#pragma unroll
    for (int n = 0; n < 2; ++n)
      bvf[ch][n] = be[ch * 128 + wn * 32 + n * 16 + lr];

  // prologue staging (r5/r8 verbatim): tile0 full + A0s1,B1s1 of tile1
  stA(0, 0, 0, true); stB(1, 0, 0, true); stA(1, 0, 0, true);
  stB(0, 0, 0, true); stA(0, 1, 1, true); stB(1, 1, 1, true);
  asm volatile("s_waitcnt vmcnt(4)" ::: "memory");  // tile0 halves landed
  __builtin_amdgcn_s_barrier();

  // fragment registers: fa (current A half), fbA = B0, fbB = B1 of the slot
  short8 fa[4][2], fbA[2][2], fbB[2][2];

#define RD_FA(SLOT, RH)                                                        \
  {                                                                            \
    const unsigned short* sA = lds + (size_t)((SLOT) * 4 + (RH)) * 8192;       \
    _Pragma("unroll") for (int m = 0; m < 4; ++m)                              \
      _Pragma("unroll") for (int kk = 0; kk < 2; ++kk) {                       \
        int row = wm * 64 + m * 16 + lr;                                       \
        fa[m][kk] = *(const short8*)(sA + row * 64 +                           \
                                     (((kk << 2) | ls) ^ (row & 7)) * 8);      \
      }                                                                        \
  }
#define RD_FB(FB, SLOT, CH)                                                    \
  {                                                                            \
    const unsigned short* sB = lds + (size_t)((SLOT) * 4 + 2 + (CH)) * 8192;   \
    _Pragma("unroll") for (int n = 0; n < 2; ++n)                              \
      _Pragma("unroll") for (int kk = 0; kk < 2; ++kk) {                       \
        int row = wn * 32 + n * 16 + lr;                                       \
        FB[n][kk] = *(const short8*)(sB + row * 64 +                           \
                                     (((kk << 2) | ls) ^ (row & 7)) * 8);      \
      }                                                                        \
  }
#define MFMA16(RH, CH, FB)                                                     \
  __builtin_amdgcn_s_setprio(1);                                               \
  _Pragma("unroll") for (int m = 0; m < 4; ++m)                                \
    _Pragma("unroll") for (int n = 0; n < 2; ++n)                              \
      _Pragma("unroll") for (int kk = 0; kk < 2; ++kk)                         \
        acc[RH][CH][m][n] = __builtin_amdgcn_mfma_f32_16x16x32_bf16(           \
            fa[m][kk], FB[n][kk], acc[RH][CH][m][n], 0, 0, 0);                 \
  __builtin_amdgcn_s_setprio(0);

#define LGKM0() asm volatile("s_waitcnt lgkmcnt(0)" ::: "memory")
#define SBAR() __builtin_amdgcn_s_barrier()

  for (int i = 0; i < NI; ++i) {
    const int t1 = 2 * i + 1, t2 = 2 * i + 2, t3 = 2 * i + 3;
    const bool v2 = t2 < NT, v3 = t3 < NT;

    // ---- P1 (s0, RH0, CH0): 12 reads ----
    RD_FA(0, 0) RD_FB(fbA, 0, 0)
    stA(1, 1, t1, true);
    SBAR(); LGKM0();
    MFMA16(0, 0, fbA)
    SBAR();
    // ---- P2 (s0, RH0, CH1): 4 reads ----
    RD_FB(fbB, 0, 1)
    stB(0, 1, t1, true);
    SBAR(); LGKM0();
    MFMA16(0, 1, fbB)
    SBAR();
    // ---- P3 (s0, RH1, CH1): 8 reads ----
    RD_FA(0, 1)
    stA(0, 0, t2, v2);
    SBAR(); LGKM0();
    MFMA16(1, 1, fbB)
    SBAR();
    // ---- P4 (s0, RH1, CH0): 0 reads; pure MFMA ----
    stB(1, 0, t2, v2);
    asm volatile("s_waitcnt vmcnt(4)" ::: "memory");
    SBAR();
    MFMA16(1, 0, fbA)
    SBAR();
    // ---- P5 (s1, RH0, CH0): 12 reads ----
    RD_FA(1, 0) RD_FB(fbA, 1, 0)
    stA(1, 0, t2, v2);
    SBAR(); LGKM0();
    MFMA16(0, 0, fbA)
    SBAR();
    // ---- P6 (s1, RH0, CH1): 4 reads ----
    RD_FB(fbB, 1, 1)
    stB(0, 0, t2, v2);
    SBAR(); LGKM0();
    MFMA16(0, 1, fbB)
    SBAR();
    // ---- P7 (s1, RH1, CH1): 8 reads ----
    RD_FA(1, 1)
    stA(0, 1, t3, v3);
    SBAR(); LGKM0();
    MFMA16(1, 1, fbB)
    SBAR();
    // ---- P8 (s1, RH1, CH0): 0 reads; pure MFMA ----
    stB(1, 1, t3, v3);
    asm volatile("s_waitcnt vmcnt(4)" ::: "memory");
    SBAR();
    MFMA16(1, 0, fbA)
    SBAR();
  }
#undef RD_FA
#undef RD_FB
#undef MFMA16
#undef LGKM0
#undef SBAR

  // drain all staging + reads before LDS reuse / exit
  asm volatile("s_waitcnt vmcnt(0) lgkmcnt(0)" ::: "memory");
  __builtin_amdgcn_s_barrier();

  if constexpr (EPI == 1) {
    // bounce: lds as [256][256] ushort, 16B-chunk XOR swizzle (ch ^= row&7)
#pragma unroll
    for (int rh = 0; rh < 2; ++rh)
#pragma unroll
      for (int ch = 0; ch < 2; ++ch)
#pragma unroll
        for (int m = 0; m < 4; ++m)
#pragma unroll
          for (int n = 0; n < 2; ++n)
#pragma unroll
            for (int i = 0; i < 4; ++i) {
              int row = rh * 128 + wm * 64 + m * 16 + ls * 4 + i;
              int col = ch * 128 + wn * 32 + n * 16 + lr;
              lds[row * 256 + (((col >> 3) ^ (row & 7)) << 3) + (col & 7)] =
                  f2b(gelu_t(acc[rh][ch][m][n][i] + bvf[ch][n]));
            }
    __builtin_amdgcn_s_barrier();
    unsigned short* H = (unsigned short*)Cout;
#pragma unroll
    for (int j = 0; j < 16; ++j) {
      int row = j * 16 + wave * 2 + (lane >> 5);
      int chk = lane & 31;
      int sc = chk ^ (row & 7);
      unsigned short* dst =
          H + ((size_t)e * Mt + mblk * 256 + row) * Nt + nblk * 256 + chk * 8;
      *(int4*)dst = *(const int4*)(lds + row * 256 + sc * 8);
    }
  } else {
    // fp32 bounce through padded LDS [256][132] f32 (fixes 64B write amp),
    // one 128-col half at a time, fully-coalesced float4 stores.
    float* fl = (float*)lds;  // 256*132*4 = 135168 B <= 147456
    float* O = (float*)Cout;
#pragma unroll
    for (int ch = 0; ch < 2; ++ch) {
#pragma unroll
      for (int rh = 0; rh < 2; ++rh)
#pragma unroll
        for (int m = 0; m < 4; ++m)
#pragma unroll
          for (int n = 0; n < 2; ++n)
#pragma unroll
            for (int i = 0; i < 4; ++i) {
              int row = rh * 128 + wm * 64 + m * 16 + ls * 4 + i;
              int colh = wn * 32 + n * 16 + lr;
              fl[row * 132 + colh] = acc[rh][ch][m][n][i] + bvf[ch][n];
            }
      __builtin_amdgcn_s_barrier();
#pragma unroll
      for (int q = 0; q < 16; ++q) {
        int idx = q * 512 + tid;
        int row = idx >> 5, cc = idx & 31;
        float* dst = O + ((size_t)e * Mt + mblk * 256 + row) * Nt +
                     nblk * 256 + ch * 128 + cc * 4;
        *(float4*)dst = *(const float4*)(fl + row * 132 + cc * 4);
      }
      if (ch == 0) __builtin_amdgcn_s_barrier();
    }
  }
}

extern "C" void kernel_launch(void* const* d_in, const int* in_sizes, int n_in,
                              void* d_out, int out_size, void* d_ws, size_t ws_size,
                              hipStream_t stream) {
  const float* x = (const float*)d_in[0];
  const float* w1 = (const float*)d_in[1];
  const float* b1 = (const float*)d_in[2];
  const float* w2 = (const float*)d_in[3];
  const float* b2 = (const float*)d_in[4];
  float* out = (float*)d_out;

  unsigned short* ws = (unsigned short*)d_ws;
  unsigned short* xb = ws;                               // [T][D] bf16
  unsigned short* w1t = xb + (size_t)T_ * D_;            // [E][F][D] bf16
  unsigned short* w2t = w1t + (size_t)E_ * F_ * D_;      // [E][D][F] bf16
  unsigned short* h = w2t + (size_t)E_ * D_ * F_;        // [T][F] bf16

  cvt_bf16_kernel<<<2048, 256, 0, stream>>>(x, xb, T_ * D_);
  transpose_cvt<<<dim3((D_ / 32) * (F_ / 32), E_), 256, 0, stream>>>(w1, w1t, D_, F_);
  transpose_cvt<<<dim3((F_ / 32) * (D_ / 32), E_), 256, 0, stream>>>(w2, w2t, F_, D_);

  gemmG<C_, F_, D_, 1>
      <<<E_ * (C_ / 256) * (F_ / 256), 512, 0, stream>>>(xb, w1t, b1, h);
  gemmG<C_, D_, F_, 2>
      <<<E_ * (C_ / 256) * (D_ / 256), 512, 0, stream>>>(h, w2t, b2, out);
}